// Round 13
// baseline (497.644 us; speedup 1.0000x reference)
//
#include <hip/hip_runtime.h>
#include <hip/hip_cooperative_groups.h>
#include <math.h>

namespace cg = cooperative_groups;

#define NN 50000
#define NE 800000
#define NP 100000
#define NEG_SLOPE 0.2f
#define LOG2E 1.4426950408889634f

// Sum over each 16-lane DPP row, entirely on the VALU pipe (no LDS/bpermute).
__device__ __forceinline__ float row_sum16(float v) {
    int x = __float_as_int(v);
    v += __int_as_float(__builtin_amdgcn_update_dpp(0, x, 0x128, 0xF, 0xF, true)); // row_ror:8
    x = __float_as_int(v);
    v += __int_as_float(__builtin_amdgcn_update_dpp(0, x, 0x124, 0xF, 0xF, true)); // row_ror:4
    x = __float_as_int(v);
    v += __int_as_float(__builtin_amdgcn_update_dpp(0, x, 0x4E, 0xF, 0xF, true));  // quad xor2
    x = __float_as_int(v);
    v += __int_as_float(__builtin_amdgcn_update_dpp(0, x, 0xB1, 0xF, 0xF, true));  // quad xor1
    return v;
}

// ---------------- CSR build: ONE cooperative kernel (was 6 launches) ----------------
// 256 blocks x 256 thr (all resident). Phases: zero -> count -> scan (one element
// per thread, intra-block prefix kept in registers across grid.sync) -> scatter.

__global__ __launch_bounds__(256) void build_csr(const int* __restrict__ src,
                                                 const int* __restrict__ dst,
                                                 int* __restrict__ cnt,
                                                 int* __restrict__ rowptr,
                                                 int* __restrict__ cursor,
                                                 int* __restrict__ csrc,
                                                 int* __restrict__ partial) {
    cg::grid_group grid = cg::this_grid();
    __shared__ int sh[4];
    int t = threadIdx.x, lane = t & 63, w = t >> 6;
    int tid = blockIdx.x * 256 + t;
    int nt = gridDim.x * 256;                 // 65536 >= NN: one element per thread
    // ---- phase 1: zero cnt
    for (int i = tid; i < NN; i += nt) cnt[i] = 0;
    grid.sync();
    // ---- phase 2: count degrees (int4 loads)
    const int4* d4v = (const int4*)dst;
    for (int i = tid; i < NE / 4; i += nt) {
        int4 d = d4v[i];
        atomicAdd(&cnt[d.x], 1);
        atomicAdd(&cnt[d.y], 1);
        atomicAdd(&cnt[d.z], 1);
        atomicAdd(&cnt[d.w], 1);
    }
    grid.sync();
    // ---- phase 3a: intra-block exclusive prefix (registers) + block sums
    int v = (tid < NN) ? cnt[tid] : 0;
    int x = v;
    #pragma unroll
    for (int mm = 1; mm < 64; mm <<= 1) {
        int y = __shfl_up(x, mm, 64);
        if (lane >= mm) x += y;
    }
    if (lane == 63) sh[w] = x;
    __syncthreads();
    int woff = 0;
    for (int k = 0; k < w; ++k) woff += sh[k];
    int myexcl = woff + x - v;                 // exclusive prefix within block
    if (t == 0) partial[blockIdx.x] = sh[0] + sh[1] + sh[2] + sh[3];
    __syncthreads();                           // sh reused in 3b
    grid.sync();
    // ---- phase 3b: block offset = sum of preceding blocks' partials
    int pv = (t < (int)blockIdx.x) ? partial[t] : 0;   // gridDim 256 == block count
    #pragma unroll
    for (int mm = 1; mm < 64; mm <<= 1) pv += __shfl_xor(pv, mm, 64);
    if (lane == 0) sh[w] = pv;
    __syncthreads();
    int blockoff = sh[0] + sh[1] + sh[2] + sh[3];
    if (tid < NN) {
        rowptr[tid] = blockoff + myexcl;
        cursor[tid] = blockoff + myexcl;
    }
    if (tid == NN - 1) rowptr[NN] = blockoff + myexcl + v;   // total == NE
    grid.sync();
    // ---- phase 4: scatter edges by dst
    const int4* s4v = (const int4*)src;
    for (int i = tid; i < NE / 4; i += nt) {
        int4 s = s4v[i];
        int4 d = d4v[i];
        int p;
        p = atomicAdd(&cursor[d.x], 1); csrc[p] = s.x;
        p = atomicAdd(&cursor[d.y], 1); csrc[p] = s.y;
        p = atomicAdd(&cursor[d.z], 1); csrc[p] = s.z;
        p = atomicAdd(&cursor[d.w], 1); csrc[p] = s.w;
    }
}

// ---------------- out[N,128] = A[N,128] @ W[128,128], 16-row x 128-col tile ----------------
// r3/r8 LDS version — the only gemm config with a healthy measured profile.
// (32-row r7: occupancy loss; SMEM r9: lgkmcnt serialization; readlane r10: VGPR blowup.)

__global__ __launch_bounds__(256) void gemm128(const float* __restrict__ A,
                                               const float* __restrict__ W,
                                               float* __restrict__ out, int nrows) {
    __shared__ float Wt[128 * 132];      // Wt[j*132+k] = W[k*128+j]
    __shared__ float rb[16 * 132];       // row tile, stride 132
    int tid = threadIdx.x;
    for (int idx = tid; idx < 128 * 128; idx += 256) {
        int k = idx >> 7, j = idx & 127;
        Wt[j * 132 + k] = W[idx];
    }
    __syncthreads();
    int lane = tid & 63, w = tid >> 6;
    int ntiles = (nrows + 15) >> 4;
    const float* w0p = &Wt[lane * 132];
    const float* w1p = &Wt[(64 + lane) * 132];
    for (int t = blockIdx.x; t < ntiles; t += gridDim.x) {
        int r0 = t << 4;
        for (int i = tid; i < 512; i += 256) {
            int rr = r0 + (i >> 5);
            float4 v = {0.f, 0.f, 0.f, 0.f};
            if (rr < nrows) v = ((const float4*)A)[(size_t)rr * 32 + (i & 31)];
            *(float4*)&rb[(i >> 5) * 132 + (i & 31) * 4] = v;
        }
        __syncthreads();
        float acc[4][2] = {};
        #pragma unroll 4
        for (int k4 = 0; k4 < 32; ++k4) {
            float4 wv0 = *(const float4*)&w0p[k4 * 4];
            float4 wv1 = *(const float4*)&w1p[k4 * 4];
            #pragma unroll
            for (int i2 = 0; i2 < 4; ++i2) {
                float4 av = *(const float4*)&rb[(w * 4 + i2) * 132 + k4 * 4];  // wave-uniform
                acc[i2][0] = fmaf(av.x, wv0.x, acc[i2][0]);
                acc[i2][0] = fmaf(av.y, wv0.y, acc[i2][0]);
                acc[i2][0] = fmaf(av.z, wv0.z, acc[i2][0]);
                acc[i2][0] = fmaf(av.w, wv0.w, acc[i2][0]);
                acc[i2][1] = fmaf(av.x, wv1.x, acc[i2][1]);
                acc[i2][1] = fmaf(av.y, wv1.y, acc[i2][1]);
                acc[i2][1] = fmaf(av.z, wv1.z, acc[i2][1]);
                acc[i2][1] = fmaf(av.w, wv1.w, acc[i2][1]);
            }
        }
        #pragma unroll
        for (int i2 = 0; i2 < 4; ++i2) {
            int rr = r0 + w * 4 + i2;
            if (rr < nrows) {
                out[(size_t)rr * 128 + lane]      = acc[i2][0];
                out[(size_t)rr * 128 + 64 + lane] = acc[i2][1];
            }
        }
        __syncthreads();
    }
}

// ---------------- fused GATv2 edge phase: one node per 32-lane half-wave ----------------
// r12 config (fabric-BW bound at ~3.45 TB/s; VALU-side changes measured neutral).

#define GAT_EDGE(fv) do {                                          \
    float ex = fv.x + fd.x; ex = fmaxf(ex, NEG_SLOPE * ex);        \
    float ey = fv.y + fd.y; ey = fmaxf(ey, NEG_SLOPE * ey);        \
    float ez = fv.z + fd.z; ez = fmaxf(ez, NEG_SLOPE * ez);        \
    float ew = fv.w + fd.w; ew = fmaxf(ew, NEG_SLOPE * ew);        \
    float part = ex * at.x + ey * at.y + ez * at.z + ew * at.w;    \
    part = row_sum16(part);                                        \
    float p = exp2f(part - m);                                     \
    s += p;                                                        \
    ax = fmaf(fv.x, p, ax);                                        \
    ay = fmaf(fv.y, p, ay);                                        \
    az = fmaf(fv.z, p, az);                                        \
    aw = fmaf(fv.w, p, aw);                                        \
} while (0)

__global__ void gat_fused(const float* __restrict__ feat,
                          const int* __restrict__ rowptr,
                          const int* __restrict__ csrc,
                          const float* __restrict__ attn,
                          const float* __restrict__ resid,
                          float* __restrict__ out) {
    int tid = blockIdx.x * blockDim.x + threadIdx.x;
    int hw = tid >> 5;                       // half-wave id = node stream
    int nhw = (gridDim.x * blockDim.x) >> 5;
    int q = threadIdx.x & 31;                // dim quad: dims 4q..4q+3
    const float4* feat4 = (const float4*)feat;
    float4 at = ((const float4*)attn)[q];
    at.x *= LOG2E; at.y *= LOG2E; at.z *= LOG2E; at.w *= LOG2E;   // scores in log2 units
    for (int d = hw; d < NN; d += nhw) {
        int beg = rowptr[d], end = rowptr[d + 1];
        float4 fd = feat4[(size_t)d * 32 + q];
        float m = 0.f, s = 0.f;
        float ax = 0.f, ay = 0.f, az = 0.f, aw = 0.f;
        int i = beg;
        float4 f0 = {0.f,0.f,0.f,0.f}, f1 = {0.f,0.f,0.f,0.f}, f2 = {0.f,0.f,0.f,0.f};
        int s3 = 0;
        if (i < end) {
            int p0 = csrc[i];
            int p1 = (i + 1 < end) ? csrc[i + 1] : 0;
            int p2 = (i + 2 < end) ? csrc[i + 2] : 0;
            int p3 = (i + 3 < end) ? csrc[i + 3] : 0;
            s3     = (i + 4 < end) ? csrc[i + 4] : 0;
            float4 fp = feat4[(size_t)p0 * 32 + q];
            if (i + 1 < end) f0 = feat4[(size_t)p1 * 32 + q];
            if (i + 2 < end) f1 = feat4[(size_t)p2 * 32 + q];
            if (i + 3 < end) f2 = feat4[(size_t)p3 * 32 + q];
            float ex = fp.x + fd.x; ex = fmaxf(ex, NEG_SLOPE * ex);
            float ey = fp.y + fd.y; ey = fmaxf(ey, NEG_SLOPE * ey);
            float ez = fp.z + fd.z; ez = fmaxf(ez, NEG_SLOPE * ez);
            float ew = fp.w + fd.w; ew = fmaxf(ew, NEG_SLOPE * ew);
            float part = ex * at.x + ey * at.y + ez * at.z + ew * at.w;
            m = row_sum16(part);             // anchor (log2 units)
            s = 1.f;
            ax = fp.x; ay = fp.y; az = fp.z; aw = fp.w;
            ++i;
        }
        while (i + 8 <= end) {
            int s4 = csrc[i + 4];
            int s5 = csrc[i + 5];
            int s6 = csrc[i + 6];
            int s7 = csrc[i + 7];
            float4 f3 = feat4[(size_t)s3 * 32 + q];
            GAT_EDGE(f0);
            f0 = feat4[(size_t)s4 * 32 + q];
            GAT_EDGE(f1);
            f1 = feat4[(size_t)s5 * 32 + q];
            GAT_EDGE(f2);
            f2 = feat4[(size_t)s6 * 32 + q];
            GAT_EDGE(f3);
            s3 = s7;
            i += 4;
        }
        while (i < end) {
            float4 f3 = {0.f, 0.f, 0.f, 0.f};
            if (i + 3 < end) f3 = feat4[(size_t)s3 * 32 + q];
            int s4 = (i + 4 < end) ? csrc[i + 4] : 0;
            GAT_EDGE(f0);
            f0 = f1; f1 = f2; f2 = f3; s3 = s4; ++i;
        }
        float inv = s > 0.f ? 1.f / s : 0.f;
        float vx = ax * inv;
        float vy = ay * inv;
        float vz = az * inv;
        float vw = aw * inv;
        if (resid) {
            float4 r = ((const float4*)resid)[(size_t)d * 32 + q];
            vx += r.x; vy += r.y; vz += r.z; vw += r.w;
        }
        vx = vx > 0.f ? vx : expm1f(vx);
        vy = vy > 0.f ? vy : expm1f(vy);
        vz = vz > 0.f ? vz : expm1f(vz);
        vw = vw > 0.f ? vw : expm1f(vw);
        float4 o; o.x = vx; o.y = vy; o.z = vz; o.w = vw;
        ((float4*)out)[(size_t)d * 32 + q] = o;
    }
}

// ---------------- predictor: r2-best config (512 thr / 8 waves / 16-edge tiles) ----------
// Settled optimum: 408 DS-instr/tile x 12 cyc x 48.8 tiles/CU == measured ~101us.
// 5 structural attacks (12w, 6w x2, 32-edge, paired-zone) all regressed.

__global__ __launch_bounds__(512, 1) void predictor(const float* __restrict__ h,
                          const int* __restrict__ ps, const int* __restrict__ pd,
                          const int* __restrict__ ns, const int* __restrict__ nd,
                          const float* __restrict__ Wp1, const float* __restrict__ bp1,
                          const float* __restrict__ Wp2, const float* __restrict__ bp2,
                          const float* __restrict__ Wp3, const float* __restrict__ bp3,
                          float* __restrict__ out) {
    __shared__ float S[29696];
    int tid = threadIdx.x;
    for (int idx = tid; idx < 128 * 64; idx += 512) {
        int k = idx >> 6, c = idx & 63;
        S[c * 132 + k] = Wp1[idx];
    }
    for (int idx = tid; idx < 64 * 64; idx += 512) {
        int k = idx >> 6, c = idx & 63;
        S[8448 + c * 68 + k] = Wp2[idx];
    }
    __syncthreads();
    int lane = tid & 63;
    int w = tid >> 6;
    int cg = lane & 15, rg = lane >> 4;
    float* zz = S + 12800 + w * 2112;          // wave-private zone: 16 x 132
    float b1v[4], b2v[4], w3v[4];
    #pragma unroll
    for (int i = 0; i < 4; ++i) {
        b1v[i] = bp1[cg + 16 * i];
        b2v[i] = bp2[cg + 16 * i];
        w3v[i] = Wp3[cg + 16 * i];
    }
    float b3 = bp3[0];
    int gw = blockIdx.x * 8 + w;
    int gnw = gridDim.x * 8;
    int ge = lane >> 2, gp = lane & 3;          // gather: local edge, quarter-row part
    const float4* h4 = (const float4*)h;
    const int NT = (2 * NP) / 16;               // 12500 tiles
    for (int T = gw; T < NT; T += gnw) {
        // ---- gather z[16][128] (elementwise product), wave-local
        int e = T * 16 + ge;
        int a, b;
        if (e < NP) { a = ps[e]; b = pd[e]; }
        else        { a = ns[e - NP]; b = nd[e - NP]; }
        const float4* pa = h4 + (size_t)a * 32 + gp;
        const float4* pb = h4 + (size_t)b * 32 + gp;
        #pragma unroll
        for (int qq = 0; qq < 8; ++qq) {
            float4 va = pa[qq * 4];
            float4 vb = pb[qq * 4];
            float4 vz;
            vz.x = va.x * vb.x; vz.y = va.y * vb.y;
            vz.z = va.z * vb.z; vz.w = va.w * vb.w;
            *(float4*)&zz[ge * 132 + gp * 4 + qq * 16] = vz;
        }
        // ---- layer 1: out1[16][64] = z @ W1
        float acc[4][4] = {};
        #pragma unroll 4
        for (int k4 = 0; k4 < 32; ++k4) {
            float4 wv[4], zv[4];
            #pragma unroll
            for (int i = 0; i < 4; ++i)
                wv[i] = *(const float4*)&S[(cg + 16 * i) * 132 + k4 * 4];
            #pragma unroll
            for (int j = 0; j < 4; ++j)
                zv[j] = *(const float4*)&zz[(rg * 4 + j) * 132 + k4 * 4];
            #pragma unroll
            for (int j = 0; j < 4; ++j) {
                #pragma unroll
                for (int i = 0; i < 4; ++i) {
                    acc[j][i] = fmaf(zv[j].x, wv[i].x, acc[j][i]);
                    acc[j][i] = fmaf(zv[j].y, wv[i].y, acc[j][i]);
                    acc[j][i] = fmaf(zv[j].z, wv[i].z, acc[j][i]);
                    acc[j][i] = fmaf(zv[j].w, wv[i].w, acc[j][i]);
                }
            }
        }
        // relu(+bias), write layer-1 activations into the overlay (stride 68)
        #pragma unroll
        for (int j = 0; j < 4; ++j) {
            #pragma unroll
            for (int i = 0; i < 4; ++i)
                zz[(rg * 4 + j) * 68 + cg + 16 * i] = fmaxf(acc[j][i] + b1v[i], 0.f);
        }
        // ---- layer 2: out2[16][64] = relu1 @ W2
        float acc2[4][4] = {};
        #pragma unroll 4
        for (int k4 = 0; k4 < 16; ++k4) {
            float4 wv[4], zv[4];
            #pragma unroll
            for (int i = 0; i < 4; ++i)
                wv[i] = *(const float4*)&S[8448 + (cg + 16 * i) * 68 + k4 * 4];
            #pragma unroll
            for (int j = 0; j < 4; ++j)
                zv[j] = *(const float4*)&zz[(rg * 4 + j) * 68 + k4 * 4];
            #pragma unroll
            for (int j = 0; j < 4; ++j) {
                #pragma unroll
                for (int i = 0; i < 4; ++i) {
                    acc2[j][i] = fmaf(zv[j].x, wv[i].x, acc2[j][i]);
                    acc2[j][i] = fmaf(zv[j].y, wv[i].y, acc2[j][i]);
                    acc2[j][i] = fmaf(zv[j].z, wv[i].z, acc2[j][i]);
                    acc2[j][i] = fmaf(zv[j].w, wv[i].w, acc2[j][i]);
                }
            }
        }
        // ---- layer 3: relu(+bias) . W3, DPP row-sum over the 16 col-groups (VALU pipe)
        float v[4];
        #pragma unroll
        for (int j = 0; j < 4; ++j) {
            float sv = 0.f;
            #pragma unroll
            for (int i = 0; i < 4; ++i)
                sv = fmaf(fmaxf(acc2[j][i] + b2v[i], 0.f), w3v[i], sv);
            v[j] = row_sum16(sv);
        }
        if (cg == 0) {
            float4 o;
            o.x = v[0] + b3; o.y = v[1] + b3; o.z = v[2] + b3; o.w = v[3] + b3;
            *(float4*)&out[T * 16 + rg * 4] = o;
        }
    }
}

extern "C" void kernel_launch(void* const* d_in, const int* in_sizes, int n_in,
                              void* d_out, int out_size, void* d_ws, size_t ws_size,
                              hipStream_t stream) {
    const float* x       = (const float*)d_in[0];
    const int*   src     = (const int*)d_in[1];
    const int*   dst     = (const int*)d_in[2];
    const int*   pos_src = (const int*)d_in[3];
    const int*   pos_dst = (const int*)d_in[4];
    const int*   neg_src = (const int*)d_in[5];
    const int*   neg_dst = (const int*)d_in[6];
    const float* W0      = (const float*)d_in[7];
    const float* attn0   = (const float*)d_in[8];
    const float* W1      = (const float*)d_in[9];
    const float* attn1   = (const float*)d_in[10];
    const float* Wp1     = (const float*)d_in[11];
    const float* bp1     = (const float*)d_in[12];
    const float* Wp2     = (const float*)d_in[13];
    const float* bp2     = (const float*)d_in[14];
    const float* Wp3     = (const float*)d_in[15];
    const float* bp3     = (const float*)d_in[16];

    float* A = (float*)d_ws;                       // feat buffer
    float* B = A + (size_t)NN * 128;               // layer-1 output (h)
    float* C = B + (size_t)NN * 128;               // layer-0 output / residual
    int* cnt     = (int*)(C + (size_t)NN * 128);   // [NN]
    int* rowptr  = cnt + NN;                       // [NN+1]
    int* cursor  = rowptr + NN + 1;                // [NN]
    int* csrc    = cursor + NN;                    // [NE]
    int* partial = csrc + NE;                      // [256]
    float* out = (float*)d_out;

    // ---- CSR by dst: single cooperative launch (was memset + 5 kernels)
    {
        void* args[] = {(void*)&src, (void*)&dst, (void*)&cnt, (void*)&rowptr,
                        (void*)&cursor, (void*)&csrc, (void*)&partial};
        hipLaunchCooperativeKernel((void*)build_csr, dim3(256), dim3(256),
                                   args, 0, stream);
    }

    // ---- layer 0: feat=A, out=C, no residual
    gemm128<<<1024, 256, 0, stream>>>(x, W0, A, NN);
    gat_fused<<<6250, 256, 0, stream>>>(A, rowptr, csrc, attn0, nullptr, C);

    // ---- layer 1: feat=A, out=B, residual=C
    gemm128<<<1024, 256, 0, stream>>>(C, W1, A, NN);
    gat_fused<<<6250, 256, 0, stream>>>(A, rowptr, csrc, attn1, C, B);

    // ---- predictor on h=B: pos -> out[0..P), neg -> out[P..2P)
    predictor<<<256, 512, 0, stream>>>(B, pos_src, pos_dst, neg_src, neg_dst,
                                       Wp1, bp1, Wp2, bp2, Wp3, bp3, out);
}

// Round 14
// 378.455 us; speedup vs baseline: 1.3149x; 1.3149x over previous
//
#include <hip/hip_runtime.h>
#include <math.h>

#define NN 50000
#define NE 800000
#define NP 100000
#define NEG_SLOPE 0.2f
#define SCAN_NB 196   // ceil(NN/256)
#define LOG2E 1.4426950408889634f
#define GEMM_BLOCKS 1024
#define COUNT_BLOCKS 782

// Sum over each 16-lane DPP row, entirely on the VALU pipe (no LDS/bpermute).
__device__ __forceinline__ float row_sum16(float v) {
    int x = __float_as_int(v);
    v += __int_as_float(__builtin_amdgcn_update_dpp(0, x, 0x128, 0xF, 0xF, true)); // row_ror:8
    x = __float_as_int(v);
    v += __int_as_float(__builtin_amdgcn_update_dpp(0, x, 0x124, 0xF, 0xF, true)); // row_ror:4
    x = __float_as_int(v);
    v += __int_as_float(__builtin_amdgcn_update_dpp(0, x, 0x4E, 0xF, 0xF, true));  // quad xor2
    x = __float_as_int(v);
    v += __int_as_float(__builtin_amdgcn_update_dpp(0, x, 0xB1, 0xF, 0xF, true));  // quad xor1
    return v;
}

// ---------------- gemm body (r3/r8 measured-best) ----------------
// stride passed explicitly so the hybrid launch (extra count blocks) keeps tile coverage.

__device__ __forceinline__ void gemm_body(const float* __restrict__ A,
                                          const float* __restrict__ W,
                                          float* __restrict__ out, int nrows,
                                          int gemm_blocks) {
    __shared__ float Wt[128 * 132];      // Wt[j*132+k] = W[k*128+j]
    __shared__ float rb[16 * 132];       // row tile, stride 132
    int tid = threadIdx.x;
    for (int idx = tid; idx < 128 * 128; idx += 256) {
        int k = idx >> 7, j = idx & 127;
        Wt[j * 132 + k] = W[idx];
    }
    __syncthreads();
    int lane = tid & 63, w = tid >> 6;
    int ntiles = (nrows + 15) >> 4;
    const float* w0p = &Wt[lane * 132];
    const float* w1p = &Wt[(64 + lane) * 132];
    for (int t = blockIdx.x; t < ntiles; t += gemm_blocks) {
        int r0 = t << 4;
        for (int i = tid; i < 512; i += 256) {
            int rr = r0 + (i >> 5);
            float4 v = {0.f, 0.f, 0.f, 0.f};
            if (rr < nrows) v = ((const float4*)A)[(size_t)rr * 32 + (i & 31)];
            *(float4*)&rb[(i >> 5) * 132 + (i & 31) * 4] = v;
        }
        __syncthreads();
        float acc[4][2] = {};
        #pragma unroll 4
        for (int k4 = 0; k4 < 32; ++k4) {
            float4 wv0 = *(const float4*)&w0p[k4 * 4];
            float4 wv1 = *(const float4*)&w1p[k4 * 4];
            #pragma unroll
            for (int i2 = 0; i2 < 4; ++i2) {
                float4 av = *(const float4*)&rb[(w * 4 + i2) * 132 + k4 * 4];  // wave-uniform
                acc[i2][0] = fmaf(av.x, wv0.x, acc[i2][0]);
                acc[i2][0] = fmaf(av.y, wv0.y, acc[i2][0]);
                acc[i2][0] = fmaf(av.z, wv0.z, acc[i2][0]);
                acc[i2][0] = fmaf(av.w, wv0.w, acc[i2][0]);
                acc[i2][1] = fmaf(av.x, wv1.x, acc[i2][1]);
                acc[i2][1] = fmaf(av.y, wv1.y, acc[i2][1]);
                acc[i2][1] = fmaf(av.z, wv1.z, acc[i2][1]);
                acc[i2][1] = fmaf(av.w, wv1.w, acc[i2][1]);
            }
        }
        #pragma unroll
        for (int i2 = 0; i2 < 4; ++i2) {
            int rr = r0 + w * 4 + i2;
            if (rr < nrows) {
                out[(size_t)rr * 128 + lane]      = acc[i2][0];
                out[(size_t)rr * 128 + 64 + lane] = acc[i2][1];
            }
        }
        __syncthreads();
    }
}

__global__ __launch_bounds__(256) void gemm128(const float* __restrict__ A,
                                               const float* __restrict__ W,
                                               float* __restrict__ out, int nrows) {
    gemm_body(A, W, out, nrows, gridDim.x);
}

// Hybrid: blocks [0,GEMM_BLOCKS) run layer-0 gemm; blocks beyond run degree-count.
// The two are data-independent; count hides under the gemm's runtime.
__global__ __launch_bounds__(256) void gemm128_count(const float* __restrict__ A,
                                                     const float* __restrict__ W,
                                                     float* __restrict__ out, int nrows,
                                                     const int* __restrict__ dst,
                                                     int* __restrict__ cnt) {
    if (blockIdx.x < GEMM_BLOCKS) {
        gemm_body(A, W, out, nrows, GEMM_BLOCKS);
    } else {
        int i = (blockIdx.x - GEMM_BLOCKS) * 256 + threadIdx.x;
        int st = COUNT_BLOCKS * 256;
        const int4* d4 = (const int4*)dst;          // NE % 4 == 0
        for (; i < NE / 4; i += st) {
            int4 d = d4[i];
            atomicAdd(&cnt[d.x], 1);
            atomicAdd(&cnt[d.y], 1);
            atomicAdd(&cnt[d.z], 1);
            atomicAdd(&cnt[d.w], 1);
        }
    }
}

// ---------------- CSR scan: partial sums -> apply (block offset computed inline) ----------

__global__ __launch_bounds__(256) void scan_part(const int* __restrict__ cnt,
                                                 int* __restrict__ partial) {
    __shared__ int ws[4];
    int t = threadIdx.x;
    int idx = blockIdx.x * 256 + t;
    int v = (idx < NN) ? cnt[idx] : 0;
    #pragma unroll
    for (int mm = 1; mm < 64; mm <<= 1) v += __shfl_xor(v, mm, 64);
    if ((t & 63) == 0) ws[t >> 6] = v;
    __syncthreads();
    if (t == 0) partial[blockIdx.x] = ws[0] + ws[1] + ws[2] + ws[3];
}

// apply: block offset = sum of preceding blocks' partials (SCAN_NB=196 <= 256, so
// thread t holds partial[t] for t < blockIdx), plus intra-block exclusive prefix.
__global__ __launch_bounds__(256) void scan_apply(const int* __restrict__ cnt,
                                                  const int* __restrict__ partial,
                                                  int* __restrict__ rowptr,
                                                  int* __restrict__ cursor) {
    __shared__ int sh[4];
    __shared__ int shb[4];
    int t = threadIdx.x, lane = t & 63, w = t >> 6;
    // block offset
    int pv = (t < (int)blockIdx.x) ? partial[t] : 0;   // blockIdx < SCAN_NB <= 256
    #pragma unroll
    for (int mm = 1; mm < 64; mm <<= 1) pv += __shfl_xor(pv, mm, 64);
    if (lane == 0) shb[w] = pv;
    // intra-block prefix
    int idx = blockIdx.x * 256 + t;
    int v = (idx < NN) ? cnt[idx] : 0;
    int x = v;
    #pragma unroll
    for (int mm = 1; mm < 64; mm <<= 1) {
        int y = __shfl_up(x, mm, 64);
        if (lane >= mm) x += y;
    }
    if (lane == 63) sh[w] = x;
    __syncthreads();
    int off = shb[0] + shb[1] + shb[2] + shb[3];
    for (int k = 0; k < w; ++k) off += sh[k];
    int excl = off + x - v;
    if (idx < NN) { rowptr[idx] = excl; cursor[idx] = excl; }
    if (idx == NN - 1) rowptr[NN] = excl + v;   // total == NE
}

__global__ void scatter_edges(const int* __restrict__ src, const int* __restrict__ dst,
                              int* __restrict__ cursor, int* __restrict__ csrc) {
    int i = blockIdx.x * blockDim.x + threadIdx.x;
    int st = gridDim.x * blockDim.x;
    const int4* s4 = (const int4*)src;
    const int4* d4 = (const int4*)dst;
    for (; i < NE / 4; i += st) {
        int4 s = s4[i];
        int4 d = d4[i];
        int p;
        p = atomicAdd(&cursor[d.x], 1); csrc[p] = s.x;
        p = atomicAdd(&cursor[d.y], 1); csrc[p] = s.y;
        p = atomicAdd(&cursor[d.z], 1); csrc[p] = s.z;
        p = atomicAdd(&cursor[d.w], 1); csrc[p] = s.w;
    }
}

// ---------------- fused GATv2 edge phase: one node per 32-lane half-wave (r12) ----------

#define GAT_EDGE(fv) do {                                          \
    float ex = fv.x + fd.x; ex = fmaxf(ex, NEG_SLOPE * ex);        \
    float ey = fv.y + fd.y; ey = fmaxf(ey, NEG_SLOPE * ey);        \
    float ez = fv.z + fd.z; ez = fmaxf(ez, NEG_SLOPE * ez);        \
    float ew = fv.w + fd.w; ew = fmaxf(ew, NEG_SLOPE * ew);        \
    float part = ex * at.x + ey * at.y + ez * at.z + ew * at.w;    \
    part = row_sum16(part);                                        \
    float p = exp2f(part - m);                                     \
    s += p;                                                        \
    ax = fmaf(fv.x, p, ax);                                        \
    ay = fmaf(fv.y, p, ay);                                        \
    az = fmaf(fv.z, p, az);                                        \
    aw = fmaf(fv.w, p, aw);                                        \
} while (0)

__global__ void gat_fused(const float* __restrict__ feat,
                          const int* __restrict__ rowptr,
                          const int* __restrict__ csrc,
                          const float* __restrict__ attn,
                          const float* __restrict__ resid,
                          float* __restrict__ out) {
    int tid = blockIdx.x * blockDim.x + threadIdx.x;
    int hw = tid >> 5;                       // half-wave id = node stream
    int nhw = (gridDim.x * blockDim.x) >> 5;
    int q = threadIdx.x & 31;                // dim quad: dims 4q..4q+3
    const float4* feat4 = (const float4*)feat;
    float4 at = ((const float4*)attn)[q];
    at.x *= LOG2E; at.y *= LOG2E; at.z *= LOG2E; at.w *= LOG2E;   // scores in log2 units
    for (int d = hw; d < NN; d += nhw) {
        int beg = rowptr[d], end = rowptr[d + 1];
        float4 fd = feat4[(size_t)d * 32 + q];
        float m = 0.f, s = 0.f;
        float ax = 0.f, ay = 0.f, az = 0.f, aw = 0.f;
        int i = beg;
        float4 f0 = {0.f,0.f,0.f,0.f}, f1 = {0.f,0.f,0.f,0.f}, f2 = {0.f,0.f,0.f,0.f};
        int s3 = 0;
        if (i < end) {
            int p0 = csrc[i];
            int p1 = (i + 1 < end) ? csrc[i + 1] : 0;
            int p2 = (i + 2 < end) ? csrc[i + 2] : 0;
            int p3 = (i + 3 < end) ? csrc[i + 3] : 0;
            s3     = (i + 4 < end) ? csrc[i + 4] : 0;
            float4 fp = feat4[(size_t)p0 * 32 + q];
            if (i + 1 < end) f0 = feat4[(size_t)p1 * 32 + q];
            if (i + 2 < end) f1 = feat4[(size_t)p2 * 32 + q];
            if (i + 3 < end) f2 = feat4[(size_t)p3 * 32 + q];
            float ex = fp.x + fd.x; ex = fmaxf(ex, NEG_SLOPE * ex);
            float ey = fp.y + fd.y; ey = fmaxf(ey, NEG_SLOPE * ey);
            float ez = fp.z + fd.z; ez = fmaxf(ez, NEG_SLOPE * ez);
            float ew = fp.w + fd.w; ew = fmaxf(ew, NEG_SLOPE * ew);
            float part = ex * at.x + ey * at.y + ez * at.z + ew * at.w;
            m = row_sum16(part);             // anchor (log2 units)
            s = 1.f;
            ax = fp.x; ay = fp.y; az = fp.z; aw = fp.w;
            ++i;
        }
        while (i + 8 <= end) {
            int s4 = csrc[i + 4];
            int s5 = csrc[i + 5];
            int s6 = csrc[i + 6];
            int s7 = csrc[i + 7];
            float4 f3 = feat4[(size_t)s3 * 32 + q];
            GAT_EDGE(f0);
            f0 = feat4[(size_t)s4 * 32 + q];
            GAT_EDGE(f1);
            f1 = feat4[(size_t)s5 * 32 + q];
            GAT_EDGE(f2);
            f2 = feat4[(size_t)s6 * 32 + q];
            GAT_EDGE(f3);
            s3 = s7;
            i += 4;
        }
        while (i < end) {
            float4 f3 = {0.f, 0.f, 0.f, 0.f};
            if (i + 3 < end) f3 = feat4[(size_t)s3 * 32 + q];
            int s4 = (i + 4 < end) ? csrc[i + 4] : 0;
            GAT_EDGE(f0);
            f0 = f1; f1 = f2; f2 = f3; s3 = s4; ++i;
        }
        float inv = s > 0.f ? 1.f / s : 0.f;
        float vx = ax * inv;
        float vy = ay * inv;
        float vz = az * inv;
        float vw = aw * inv;
        if (resid) {
            float4 r = ((const float4*)resid)[(size_t)d * 32 + q];
            vx += r.x; vy += r.y; vz += r.z; vw += r.w;
        }
        vx = vx > 0.f ? vx : expm1f(vx);
        vy = vy > 0.f ? vy : expm1f(vy);
        vz = vz > 0.f ? vz : expm1f(vz);
        vw = vw > 0.f ? vw : expm1f(vw);
        float4 o; o.x = vx; o.y = vy; o.z = vz; o.w = vw;
        ((float4*)out)[(size_t)d * 32 + q] = o;
    }
}

// ---------------- predictor: r2-best config (512 thr / 8 waves / 16-edge tiles) ----------
// Settled optimum: 408 DS-instr/tile x 12 cyc x 48.8 tiles/CU == measured ~101us.

__global__ __launch_bounds__(512, 1) void predictor(const float* __restrict__ h,
                          const int* __restrict__ ps, const int* __restrict__ pd,
                          const int* __restrict__ ns, const int* __restrict__ nd,
                          const float* __restrict__ Wp1, const float* __restrict__ bp1,
                          const float* __restrict__ Wp2, const float* __restrict__ bp2,
                          const float* __restrict__ Wp3, const float* __restrict__ bp3,
                          float* __restrict__ out) {
    __shared__ float S[29696];
    int tid = threadIdx.x;
    for (int idx = tid; idx < 128 * 64; idx += 512) {
        int k = idx >> 6, c = idx & 63;
        S[c * 132 + k] = Wp1[idx];
    }
    for (int idx = tid; idx < 64 * 64; idx += 512) {
        int k = idx >> 6, c = idx & 63;
        S[8448 + c * 68 + k] = Wp2[idx];
    }
    __syncthreads();
    int lane = tid & 63;
    int w = tid >> 6;
    int cg = lane & 15, rg = lane >> 4;
    float* zz = S + 12800 + w * 2112;          // wave-private zone: 16 x 132
    float b1v[4], b2v[4], w3v[4];
    #pragma unroll
    for (int i = 0; i < 4; ++i) {
        b1v[i] = bp1[cg + 16 * i];
        b2v[i] = bp2[cg + 16 * i];
        w3v[i] = Wp3[cg + 16 * i];
    }
    float b3 = bp3[0];
    int gw = blockIdx.x * 8 + w;
    int gnw = gridDim.x * 8;
    int ge = lane >> 2, gp = lane & 3;          // gather: local edge, quarter-row part
    const float4* h4 = (const float4*)h;
    const int NT = (2 * NP) / 16;               // 12500 tiles
    for (int T = gw; T < NT; T += gnw) {
        // ---- gather z[16][128] (elementwise product), wave-local
        int e = T * 16 + ge;
        int a, b;
        if (e < NP) { a = ps[e]; b = pd[e]; }
        else        { a = ns[e - NP]; b = nd[e - NP]; }
        const float4* pa = h4 + (size_t)a * 32 + gp;
        const float4* pb = h4 + (size_t)b * 32 + gp;
        #pragma unroll
        for (int qq = 0; qq < 8; ++qq) {
            float4 va = pa[qq * 4];
            float4 vb = pb[qq * 4];
            float4 vz;
            vz.x = va.x * vb.x; vz.y = va.y * vb.y;
            vz.z = va.z * vb.z; vz.w = va.w * vb.w;
            *(float4*)&zz[ge * 132 + gp * 4 + qq * 16] = vz;
        }
        // ---- layer 1: out1[16][64] = z @ W1
        float acc[4][4] = {};
        #pragma unroll 4
        for (int k4 = 0; k4 < 32; ++k4) {
            float4 wv[4], zv[4];
            #pragma unroll
            for (int i = 0; i < 4; ++i)
                wv[i] = *(const float4*)&S[(cg + 16 * i) * 132 + k4 * 4];
            #pragma unroll
            for (int j = 0; j < 4; ++j)
                zv[j] = *(const float4*)&zz[(rg * 4 + j) * 132 + k4 * 4];
            #pragma unroll
            for (int j = 0; j < 4; ++j) {
                #pragma unroll
                for (int i = 0; i < 4; ++i) {
                    acc[j][i] = fmaf(zv[j].x, wv[i].x, acc[j][i]);
                    acc[j][i] = fmaf(zv[j].y, wv[i].y, acc[j][i]);
                    acc[j][i] = fmaf(zv[j].z, wv[i].z, acc[j][i]);
                    acc[j][i] = fmaf(zv[j].w, wv[i].w, acc[j][i]);
                }
            }
        }
        // relu(+bias), write layer-1 activations into the overlay (stride 68)
        #pragma unroll
        for (int j = 0; j < 4; ++j) {
            #pragma unroll
            for (int i = 0; i < 4; ++i)
                zz[(rg * 4 + j) * 68 + cg + 16 * i] = fmaxf(acc[j][i] + b1v[i], 0.f);
        }
        // ---- layer 2: out2[16][64] = relu1 @ W2
        float acc2[4][4] = {};
        #pragma unroll 4
        for (int k4 = 0; k4 < 16; ++k4) {
            float4 wv[4], zv[4];
            #pragma unroll
            for (int i = 0; i < 4; ++i)
                wv[i] = *(const float4*)&S[8448 + (cg + 16 * i) * 68 + k4 * 4];
            #pragma unroll
            for (int j = 0; j < 4; ++j)
                zv[j] = *(const float4*)&zz[(rg * 4 + j) * 68 + k4 * 4];
            #pragma unroll
            for (int j = 0; j < 4; ++j) {
                #pragma unroll
                for (int i = 0; i < 4; ++i) {
                    acc2[j][i] = fmaf(zv[j].x, wv[i].x, acc2[j][i]);
                    acc2[j][i] = fmaf(zv[j].y, wv[i].y, acc2[j][i]);
                    acc2[j][i] = fmaf(zv[j].z, wv[i].z, acc2[j][i]);
                    acc2[j][i] = fmaf(zv[j].w, wv[i].w, acc2[j][i]);
                }
            }
        }
        // ---- layer 3: relu(+bias) . W3, DPP row-sum over the 16 col-groups (VALU pipe)
        float v[4];
        #pragma unroll
        for (int j = 0; j < 4; ++j) {
            float sv = 0.f;
            #pragma unroll
            for (int i = 0; i < 4; ++i)
                sv = fmaf(fmaxf(acc2[j][i] + b2v[i], 0.f), w3v[i], sv);
            v[j] = row_sum16(sv);
        }
        if (cg == 0) {
            float4 o;
            o.x = v[0] + b3; o.y = v[1] + b3; o.z = v[2] + b3; o.w = v[3] + b3;
            *(float4*)&out[T * 16 + rg * 4] = o;
        }
    }
}

extern "C" void kernel_launch(void* const* d_in, const int* in_sizes, int n_in,
                              void* d_out, int out_size, void* d_ws, size_t ws_size,
                              hipStream_t stream) {
    const float* x       = (const float*)d_in[0];
    const int*   src     = (const int*)d_in[1];
    const int*   dst     = (const int*)d_in[2];
    const int*   pos_src = (const int*)d_in[3];
    const int*   pos_dst = (const int*)d_in[4];
    const int*   neg_src = (const int*)d_in[5];
    const int*   neg_dst = (const int*)d_in[6];
    const float* W0      = (const float*)d_in[7];
    const float* attn0   = (const float*)d_in[8];
    const float* W1      = (const float*)d_in[9];
    const float* attn1   = (const float*)d_in[10];
    const float* Wp1     = (const float*)d_in[11];
    const float* bp1     = (const float*)d_in[12];
    const float* Wp2     = (const float*)d_in[13];
    const float* bp2     = (const float*)d_in[14];
    const float* Wp3     = (const float*)d_in[15];
    const float* bp3     = (const float*)d_in[16];

    float* A = (float*)d_ws;                       // feat buffer
    float* B = A + (size_t)NN * 128;               // layer-1 output (h)
    float* C = B + (size_t)NN * 128;               // layer-0 output / residual
    int* cnt     = (int*)(C + (size_t)NN * 128);   // [NN]
    int* rowptr  = cnt + NN;                       // [NN+1]
    int* cursor  = rowptr + NN + 1;                // [NN]
    int* csrc    = cursor + NN;                    // [NE]
    int* partial = csrc + NE;                      // [SCAN_NB]
    float* out = (float*)d_out;

    // ---- layer-0 gemm + degree count (independent, fused into one dispatch)
    hipMemsetAsync(cnt, 0, NN * sizeof(int), stream);
    gemm128_count<<<GEMM_BLOCKS + COUNT_BLOCKS, 256, 0, stream>>>(x, W0, A, NN, dst, cnt);

    // ---- CSR scan + scatter
    scan_part<<<SCAN_NB, 256, 0, stream>>>(cnt, partial);
    scan_apply<<<SCAN_NB, 256, 0, stream>>>(cnt, partial, rowptr, cursor);
    scatter_edges<<<782, 256, 0, stream>>>(src, dst, cursor, csrc);

    // ---- layer 0 edge phase: feat=A, out=C, no residual
    gat_fused<<<6250, 256, 0, stream>>>(A, rowptr, csrc, attn0, nullptr, C);

    // ---- layer 1: feat=A, out=B, residual=C
    gemm128<<<1024, 256, 0, stream>>>(C, W1, A, NN);
    gat_fused<<<6250, 256, 0, stream>>>(A, rowptr, csrc, attn1, C, B);

    // ---- predictor on h=B: pos -> out[0..P), neg -> out[P..2P)
    predictor<<<256, 512, 0, stream>>>(B, pos_src, pos_dst, neg_src, neg_dst,
                                       Wp1, bp1, Wp2, bp2, Wp3, bp3, out);
}